// Round 8
// baseline (301.047 us; speedup 1.0000x reference)
//
#include <hip/hip_runtime.h>

#define NH 8
#define HD 32
#define NL 4
#define NP 4
#define DM 256
#define LEN_IN_C 13294
#define LQ_C 13294
#define B_C 2
#define M_TOTAL (B_C * LQ_C)           // 26588
#define MT_TILES 1662                  // ceil(26588/16)
#define MT_PAD 1664                    // 26624 rows = 208 row-blocks of 128
#define RB128 208

typedef __attribute__((ext_vector_type(8))) short short8;
typedef __attribute__((ext_vector_type(4))) float floatx4;

__device__ __forceinline__ unsigned short f2bf(float x) {
    union { float f; unsigned int u; } a; a.f = x;
    unsigned int r = (a.u + 0x7FFFu + ((a.u >> 16) & 1u)) >> 16;
    return (unsigned short)r;
}
__device__ __forceinline__ float bflo(unsigned int u) {
    union { unsigned int u; float f; } a; a.u = u << 16; return a.f;
}
__device__ __forceinline__ float bfhi(unsigned int u) {
    union { unsigned int u; float f; } a; a.u = u & 0xffff0000u; return a.f;
}

// async global->LDS, 16 B per lane: LDS dest = uniform base + lane*16
__device__ __forceinline__ void glds16(const void* g, void* l) {
    __builtin_amdgcn_global_load_lds(
        (const __attribute__((address_space(1))) unsigned int*)g,
        (__attribute__((address_space(3))) unsigned int*)l, 16, 0, 0);
}

// ---------------------------------------------------------------------------
// conv_all: A-activation conversion (both matrices) + all weight conversions
// + bias fuse in ONE launch. A: [M,256] fp32 -> swizzled bf16 fragments
// (padded to MT_PAD row-tiles, zero-filled).
// Unit u = (rt*8+kc)*64+lane; lane = m+16*q holds A[rt*16+m][kc*32+q*8..+8].
// ---------------------------------------------------------------------------
__device__ __forceinline__ void conv_b_body(const float* __restrict__ W,
                                            unsigned short* __restrict__ Bsw,
                                            int Nsrc, int NTsrc, int NTtotal, int ntOff,
                                            int vblk) {
    const int u = vblk * 256 + threadIdx.x;
    const int lane = u & 63;
    const int unit = u >> 6;
    const int ntl = unit % NTsrc;
    const int kc = unit / NTsrc;
    const int n = ntl * 16 + (lane & 15);
    const int k0 = kc * 32 + (lane >> 4) * 8;
    short8 v;
#pragma unroll
    for (int j = 0; j < 8; ++j)
        v[j] = (short)f2bf(W[(size_t)(k0 + j) * Nsrc + n]);
    ((short8*)Bsw)[(size_t)(kc * NTtotal + ntOff + ntl) * 64 + lane] = v;
}

__global__ __launch_bounds__(256) void conv_all_kernel(const float* __restrict__ A0,
                                                       unsigned short* __restrict__ D0,
                                                       const float* __restrict__ A1,
                                                       unsigned short* __restrict__ D1,
                                                       const float* __restrict__ Wv,
                                                       const float* __restrict__ Woff,
                                                       const float* __restrict__ Wattn,
                                                       const float* __restrict__ Wout,
                                                       const float* __restrict__ boff,
                                                       const float* __restrict__ battn,
                                                       unsigned short* __restrict__ BswV,
                                                       unsigned short* __restrict__ BswOA,
                                                       unsigned short* __restrict__ BswO,
                                                       float* __restrict__ fbias,
                                                       int M) {
    const int bx = blockIdx.x;
    if (bx < MT_PAD * 2) {
        const float* A = blockIdx.y ? A1 : A0;
        unsigned short* Asw = blockIdx.y ? D1 : D0;
        const int u = bx * 256 + threadIdx.x;
        const int lane = u & 63;
        const int kc = (u >> 6) & 7;
        const int rt = u >> 9;
        const int row = rt * 16 + (lane & 15);
        const int col0 = kc * 32 + (lane >> 4) * 8;
        unsigned short tmp[8];
        if (row < M) {
            const float4 f0 = *(const float4*)(A + (size_t)row * 256 + col0);
            const float4 f1 = *(const float4*)(A + (size_t)row * 256 + col0 + 4);
            tmp[0] = f2bf(f0.x); tmp[1] = f2bf(f0.y); tmp[2] = f2bf(f0.z); tmp[3] = f2bf(f0.w);
            tmp[4] = f2bf(f1.x); tmp[5] = f2bf(f1.y); tmp[6] = f2bf(f1.z); tmp[7] = f2bf(f1.w);
        } else {
#pragma unroll
            for (int j = 0; j < 8; ++j) tmp[j] = 0;
        }
        short8 v;
#pragma unroll
        for (int j = 0; j < 8; ++j) v[j] = (short)tmp[j];
        ((short8*)Asw)[u] = v;
    } else {
        const int wblk = (bx - MT_PAD * 2) + 57 * blockIdx.y;   // 0..113
        if (wblk < 32)       conv_b_body(Wv,    BswV,  256, 16, 16, 0,  wblk);
        else if (wblk < 64)  conv_b_body(Woff,  BswOA, 256, 16, 24, 0,  wblk - 32);
        else if (wblk < 80)  conv_b_body(Wattn, BswOA, 128,  8, 24, 16, wblk - 64);
        else if (wblk < 112) conv_b_body(Wout,  BswO,  256, 16, 16, 0,  wblk - 80);
        else {
            const int t = threadIdx.x;
            if (t < 384) fbias[t] = (t < 256) ? boff[t] : battn[t - 256];
        }
    }
}

// ---------------------------------------------------------------------------
// m97-shape GEMM: 128x128 block, BK=32, double-buffered LDS (2x(8+8) KB).
// 4 waves in 2x2 grid; per K-iter per wave: 4 glds16 + 8 ds_read_b128 +
// 16 MFMA + 1 barrier. 8 K-iters (K=256).
// ---------------------------------------------------------------------------
template <bool OUT_BF16, int NT_B, int NCOLS>
__device__ __forceinline__ void gemm128_body(short8* As, short8* Bs,
                                             const short8* __restrict__ Au,
                                             const short8* __restrict__ Bu,
                                             int rb, int ntB,
                                             const float* __restrict__ bias,
                                             void* __restrict__ Cout, int M) {
    const int tid = threadIdx.x;
    const int lane = tid & 63;
    const int wave = tid >> 6;
    const int wr = wave >> 1;        // row half (0,1)
    const int wc = wave & 1;         // col half (0,1)
    const int rb8 = rb * 8;          // row-tile base

#define STAGE(KC, BUF)                                                              \
    {                                                                               \
        _Pragma("unroll")                                                           \
        for (int i = 0; i < 4; ++i) {                                               \
            const int u = wave * 4 + i;                                             \
            if (u < 8)                                                              \
                glds16(&Au[(size_t)((rb8 + u) * 8 + (KC)) * 64 + lane],             \
                       &As[((BUF) * 8 + u) * 64]);                                  \
            else                                                                    \
                glds16(&Bu[(size_t)((KC) * NT_B + ntB + (u - 8)) * 64 + lane],      \
                       &Bs[((BUF) * 8 + (u - 8)) * 64]);                            \
        }                                                                           \
    }

    STAGE(0, 0);
    __syncthreads();

    floatx4 acc[4][4];
#pragma unroll
    for (int i = 0; i < 4; ++i)
#pragma unroll
        for (int j = 0; j < 4; ++j) acc[i][j] = (floatx4){0.f, 0.f, 0.f, 0.f};

#pragma unroll
    for (int kc = 0; kc < 8; ++kc) {
        if (kc < 7) STAGE(kc + 1, (kc + 1) & 1);
        const int cur = kc & 1;
        short8 a[4], b[4];
#pragma unroll
        for (int i = 0; i < 4; ++i) a[i] = As[(cur * 8 + wr * 4 + i) * 64 + lane];
#pragma unroll
        for (int j = 0; j < 4; ++j) b[j] = Bs[(cur * 8 + wc * 4 + j) * 64 + lane];
#pragma unroll
        for (int i = 0; i < 4; ++i)
#pragma unroll
            for (int j = 0; j < 4; ++j)
                acc[i][j] = __builtin_amdgcn_mfma_f32_16x16x32_bf16(a[i], b[j], acc[i][j], 0, 0, 0);
        __syncthreads();
    }
#undef STAGE

    const int colq = lane & 15;
    const int rowq = (lane >> 4) * 4;
#pragma unroll
    for (int j = 0; j < 4; ++j) {
        const int col = (ntB + wc * 4 + j) * 16 + colq;
        const float bc = bias[col];
#pragma unroll
        for (int i = 0; i < 4; ++i) {
#pragma unroll
            for (int reg = 0; reg < 4; ++reg) {
                const int row = (rb8 + wr * 4 + i) * 16 + rowq + reg;
                if (row < M) {
                    const float v = acc[i][j][reg] + bc;
                    if (OUT_BF16)
                        ((unsigned short*)Cout)[(size_t)row * NCOLS + col] = f2bf(v);
                    else
                        ((float*)Cout)[(size_t)row * NCOLS + col] = v;
                }
            }
        }
    }
}

// dual: grid(5, 208). x=0,1: value colblocks (bf16 out, [M][256]);
// x=2..4: fused colblocks (fp32, 384 cols).
__global__ __launch_bounds__(256, 3) void dual_gemm_kernel(const short8* __restrict__ AuV,
                                                           const short8* __restrict__ AuQ,
                                                           const short8* __restrict__ BuV,
                                                           const short8* __restrict__ BuOA,
                                                           const float* __restrict__ bv,
                                                           const float* __restrict__ fbias,
                                                           unsigned short* __restrict__ value,
                                                           float* __restrict__ fused, int M) {
    __shared__ short8 As[2 * 8 * 64];   // 16 KB
    __shared__ short8 Bs[2 * 8 * 64];   // 16 KB
    const int rb = blockIdx.y;
    const int x = blockIdx.x;
    if (x < 2)
        gemm128_body<true, 16, 256>(As, Bs, AuV, BuV, rb, x * 8, bv, value, M);
    else
        gemm128_body<false, 24, 384>(As, Bs, AuQ, BuOA, rb, (x - 2) * 8, fbias, fused, M);
}

__global__ __launch_bounds__(256, 3) void out_gemm_kernel(const short8* __restrict__ AuAcc,
                                                          const short8* __restrict__ BuO,
                                                          const float* __restrict__ bout,
                                                          float* __restrict__ out, int M) {
    __shared__ short8 As[2 * 8 * 64];
    __shared__ short8 Bs[2 * 8 * 64];
    gemm128_body<false, 16, 256>(As, Bs, AuAcc, BuO, blockIdx.y, blockIdx.x * 8, bout, out, M);
}

// ---------------------------------------------------------------------------
// Sampler v5: 8 queries/block; value row-major [M][256] bf16 (R6-proven
// gather locality). Phase 2: 4 lanes per head, each owns 8 dims via one
// uint4 (16 B) load per corner -> half the VMEM instructions of R6.
// Output written directly in swizzled bf16 A-fragment layout (uint4 store).
// ---------------------------------------------------------------------------
__global__ __launch_bounds__(256, 4) void msda_sample_kernel(const float* __restrict__ refp,
                                                             const unsigned short* __restrict__ value,
                                                             const float* __restrict__ fused,
                                                             unsigned short* __restrict__ AccSw) {
    constexpr int lvl_hw[4] = {100, 50, 25, 13};
    constexpr int lvl_s[4] = {0, 10000, 12500, 13125};

    const int bq0 = blockIdx.x * 8;
    const int tid = threadIdx.x;

    __shared__ float s_ref[64];
    __shared__ int4 s_pi[8 * 8 * 17];
    __shared__ float4 s_pw[8 * 8 * 17];

    if (tid < 64) {
        const int idx = bq0 * 8 + tid;
        s_ref[tid] = refp[min((size_t)idx, (size_t)M_TOTAL * 8 - 1)];
    }
    __syncthreads();

#pragma unroll
    for (int jj = 0; jj < 4; ++jj) {
        const int job = jj * 256 + tid;          // 0..1023
        const int qq = job >> 7;                 // 0..7
        const int t = job & 127;                 // point id within query
        const int h = t >> 4;
        const int l = (t >> 2) & 3;
        const int bq = min(bq0 + qq, M_TOTAL - 1);
        const int b = (bq >= LQ_C) ? 1 : 0;

        const float logit = fused[(size_t)bq * 384 + 256 + t];
        float mx = logit;
#pragma unroll
        for (int mask = 1; mask < 16; mask <<= 1) mx = fmaxf(mx, __shfl_xor(mx, mask));
        const float e = expf(logit - mx);
        float s = e;
#pragma unroll
        for (int mask = 1; mask < 16; mask <<= 1) s += __shfl_xor(s, mask);
        const float aw = e / s;

        const int whl = lvl_hw[l];
        const float fwh = (float)whl;
        const float2 oxy = *(const float2*)(fused + (size_t)bq * 384 + t * 2);
        const float x = s_ref[qq * 8 + l * 2] * fwh + oxy.x - 0.5f;
        const float y = s_ref[qq * 8 + l * 2 + 1] * fwh + oxy.y - 0.5f;
        const float x0f = floorf(x), y0f = floorf(y);
        const float tx = x - x0f, ty = y - y0f;
        const int ix0 = (int)x0f, iy0 = (int)y0f;

        const bool xv0 = (unsigned)ix0 < (unsigned)whl;
        const bool xv1 = (unsigned)(ix0 + 1) < (unsigned)whl;
        const bool yv0 = (unsigned)iy0 < (unsigned)whl;
        const bool yv1 = (unsigned)(iy0 + 1) < (unsigned)whl;

        const int cx0 = min(max(ix0, 0), whl - 1);
        const int cx1 = min(max(ix0 + 1, 0), whl - 1);
        const int cy0 = min(max(iy0, 0), whl - 1);
        const int cy1 = min(max(iy0 + 1, 0), whl - 1);

        const int base = (b * LEN_IN_C + lvl_s[l]) * 256 + h * 32;
        const int r0 = base + cy0 * (whl * 256);
        const int r1 = base + cy1 * (whl * 256);
        int4 ii;                                  // BYTE offsets of the 4 corners
        ii.x = (r0 + cx0 * 256) * 2;
        ii.y = (r0 + cx1 * 256) * 2;
        ii.z = (r1 + cx0 * 256) * 2;
        ii.w = (r1 + cx1 * 256) * 2;
        float4 wv;
        wv.x = (xv0 && yv0) ? aw * (1.f - tx) * (1.f - ty) : 0.f;
        wv.y = (xv1 && yv0) ? aw * tx * (1.f - ty) : 0.f;
        wv.z = (xv0 && yv1) ? aw * (1.f - tx) * ty : 0.f;
        wv.w = (xv1 && yv1) ? aw * tx * ty : 0.f;
        const int slot = (qq * 8 + h) * 17 + (t & 15);
        s_pi[slot] = ii;
        s_pw[slot] = wv;
    }
    __syncthreads();

    const int qq = tid >> 5;          // 0..7
    const int h = (tid >> 2) & 7;
    const int d8 = tid & 3;           // owns dims d8*8 .. d8*8+7
    const char* vbp = (const char*)value + d8 * 16;
    const int pbase = (qq * 8 + h) * 17;

    float acc[8] = {0.f, 0.f, 0.f, 0.f, 0.f, 0.f, 0.f, 0.f};
#pragma unroll
    for (int g = 0; g < 8; ++g) {
        int4 ii[2]; float4 ww[2]; uint4 v[8];
#pragma unroll
        for (int p = 0; p < 2; ++p) {
            ii[p] = s_pi[pbase + g * 2 + p];
            ww[p] = s_pw[pbase + g * 2 + p];
        }
#pragma unroll
        for (int p = 0; p < 2; ++p) {
            v[p * 4 + 0] = *(const uint4*)(vbp + ii[p].x);
            v[p * 4 + 1] = *(const uint4*)(vbp + ii[p].y);
            v[p * 4 + 2] = *(const uint4*)(vbp + ii[p].z);
            v[p * 4 + 3] = *(const uint4*)(vbp + ii[p].w);
        }
#pragma unroll
        for (int p = 0; p < 2; ++p) {
            const float w[4] = {ww[p].x, ww[p].y, ww[p].z, ww[p].w};
#pragma unroll
            for (int c = 0; c < 4; ++c) {
                const uint4 vv = v[p * 4 + c];
                acc[0] += w[c] * bflo(vv.x); acc[1] += w[c] * bfhi(vv.x);
                acc[2] += w[c] * bflo(vv.y); acc[3] += w[c] * bfhi(vv.y);
                acc[4] += w[c] * bflo(vv.z); acc[5] += w[c] * bfhi(vv.z);
                acc[6] += w[c] * bflo(vv.w); acc[7] += w[c] * bfhi(vv.w);
            }
        }
    }

    // write swizzled A-fragment: row = bq, cols h*32 + d8*8 + (0..7)
    const int bq = bq0 + qq;
    if (bq < M_TOTAL) {
        const int rt = bq >> 4, mm = bq & 15;
        uint4 pk;
        pk.x = (unsigned)f2bf(acc[0]) | ((unsigned)f2bf(acc[1]) << 16);
        pk.y = (unsigned)f2bf(acc[2]) | ((unsigned)f2bf(acc[3]) << 16);
        pk.z = (unsigned)f2bf(acc[4]) | ((unsigned)f2bf(acc[5]) << 16);
        pk.w = (unsigned)f2bf(acc[6]) | ((unsigned)f2bf(acc[7]) << 16);
        *(uint4*)(AccSw + (size_t)((rt * 8 + h) * 64 + (d8 * 16 + mm)) * 8) = pk;
    }
}

extern "C" void kernel_launch(void* const* d_in, const int* in_sizes, int n_in,
                              void* d_out, int out_size, void* d_ws, size_t ws_size,
                              hipStream_t stream) {
    const float* query  = (const float*)d_in[0];
    const float* refp   = (const float*)d_in[1];
    const float* inflat = (const float*)d_in[2];
    const float* Wv    = (const float*)d_in[4];
    const float* bv    = (const float*)d_in[5];
    const float* Woff  = (const float*)d_in[6];
    const float* boff  = (const float*)d_in[7];
    const float* Wattn = (const float*)d_in[8];
    const float* battn = (const float*)d_in[9];
    const float* Wout  = (const float*)d_in[10];
    const float* bout  = (const float*)d_in[11];
    float* out = (float*)d_out;

    char* p = (char*)d_ws;
    const size_t aswBytes = (size_t)MT_PAD * 8 * 64 * 8 * sizeof(unsigned short); // 13.63 MB
    unsigned short* AswV = (unsigned short*)p;           p += aswBytes;  // value A-frags / AccSw
    unsigned short* AswQ = (unsigned short*)p;           p += aswBytes;
    unsigned short* BswV = (unsigned short*)p;           p += (size_t)8 * 16 * 64 * 8 * 2;
    unsigned short* BswOA = (unsigned short*)p;          p += (size_t)8 * 24 * 64 * 8 * 2;
    unsigned short* BswO = (unsigned short*)p;           p += (size_t)8 * 16 * 64 * 8 * 2;
    float* fbias = (float*)p;                            p += 384 * sizeof(float);
    unsigned short* value = (unsigned short*)p;          p += (size_t)M_TOTAL * 256 * 2;
    float* fused = (float*)p;                            p += (size_t)M_TOTAL * 384 * 4;
    unsigned short* AccSw = AswV;   // alias: dual consumes AswV before sampler writes

    const int M = M_TOTAL;

    conv_all_kernel<<<dim3(MT_PAD * 2 + 57, 2), 256, 0, stream>>>(
        inflat, AswV, query, AswQ, Wv, Woff, Wattn, Wout, boff, battn,
        BswV, BswOA, BswO, fbias, M);
    dual_gemm_kernel<<<dim3(5, RB128), 256, 0, stream>>>(
        (const short8*)AswV, (const short8*)AswQ,
        (const short8*)BswV, (const short8*)BswOA,
        bv, fbias, value, fused, M);
    msda_sample_kernel<<<(M + 7) / 8, 256, 0, stream>>>(refp, value, fused, AccSw);
    out_gemm_kernel<<<dim3(2, RB128), 256, 0, stream>>>(
        (const short8*)AccSw, (const short8*)BswO, bout, out, M);
}